// Round 9
// baseline (178.362 us; speedup 1.0000x reference)
//
#include <hip/hip_runtime.h>

#define S_TOK 8192
#define M_DIM 512
#define E_NUM 8
#define CAP   1024
#define H_DIM 1024
#define NGATE_BLK (S_TOK / 4)

typedef __attribute__((ext_vector_type(8))) short bf16x8;
typedef __attribute__((ext_vector_type(16))) float f32x16;

__device__ static inline unsigned short f2bf(float f) {
    unsigned int u = __float_as_uint(f);
    unsigned int r = (u + 0x7fffu + ((u >> 16) & 1u)) >> 16;
    return (unsigned short)r;
}

__device__ static inline void async_copy16(const void* g, void* l) {
    __builtin_amdgcn_global_load_lds(
        (const __attribute__((address_space(1))) void*)g,
        (__attribute__((address_space(3))) void*)l, 16, 0, 0);
}

// ---------------------------------------------------------------------------
// K1: gating + x->bf16 conversion. One wave per token.
// ---------------------------------------------------------------------------
__global__ __launch_bounds__(256) void gate_kernel(
    const float* __restrict__ feats, const float* __restrict__ wg,
    int* __restrict__ idx, float* __restrict__ gate_top,
    float* __restrict__ gates_psum, unsigned short* __restrict__ xb)
{
    __shared__ float gsh[4][8];
    const int wave = threadIdx.x >> 6;
    const int lane = threadIdx.x & 63;
    const int s = blockIdx.x * 4 + wave;

    const float* xrow = feats + (size_t)s * M_DIM;
    const int m0 = lane * 8;

    const float4 va = *(const float4*)(xrow + m0);
    const float4 vb = *(const float4*)(xrow + m0 + 4);
    float xv[8] = {va.x, va.y, va.z, va.w, vb.x, vb.y, vb.z, vb.w};

    {
        bf16x8 o;
#pragma unroll
        for (int j = 0; j < 8; ++j) o[j] = (short)f2bf(xv[j]);
        *(bf16x8*)(xb + (size_t)s * M_DIM + m0) = o;
        if (blockIdx.x == 0 && wave == 0) {
            bf16x8 z = (bf16x8){0,0,0,0,0,0,0,0};
            *(bf16x8*)(xb + (size_t)S_TOK * M_DIM + m0) = z;
        }
    }

    float p[8];
#pragma unroll
    for (int e = 0; e < 8; ++e) p[e] = 0.f;
#pragma unroll
    for (int j = 0; j < 8; ++j) {
        const float4 wa = *(const float4*)(wg + (m0 + j) * 8);
        const float4 wb2 = *(const float4*)(wg + (m0 + j) * 8 + 4);
        const float x = xv[j];
        p[0] += x * wa.x;  p[1] += x * wa.y;  p[2] += x * wa.z;  p[3] += x * wa.w;
        p[4] += x * wb2.x; p[5] += x * wb2.y; p[6] += x * wb2.z; p[7] += x * wb2.w;
    }
#pragma unroll
    for (int e = 0; e < 8; ++e) {
        float v = p[e];
#pragma unroll
        for (int off = 1; off < 64; off <<= 1) v += __shfl_xor(v, off, 64);
        p[e] = v;
    }
    if (lane == 0) {
        float mx = p[0];
#pragma unroll
        for (int e = 1; e < 8; ++e) mx = fmaxf(mx, p[e]);
        float ex[8], sum = 0.f;
#pragma unroll
        for (int e = 0; e < 8; ++e) { ex[e] = expf(p[e] - mx); sum += ex[e]; }
        const float inv = 1.0f / sum;
        int best = 0; float bl = p[0];
#pragma unroll
        for (int e = 1; e < 8; ++e) { if (p[e] > bl) { bl = p[e]; best = e; } }
#pragma unroll
        for (int e = 0; e < 8; ++e) gsh[wave][e] = ex[e] * inv;
        idx[s] = best;
        gate_top[s] = ex[best] * inv;
    }
    __syncthreads();
    if (threadIdx.x < 8) {
        const int e = threadIdx.x;
        gates_psum[blockIdx.x * 8 + e] =
            gsh[0][e] + gsh[1][e] + gsh[2][e] + gsh[3][e];
    }
}

// ---------------------------------------------------------------------------
// K2 "mid": block 0 = scan (token routing, capacity, l_aux, zero dropped
// rows); blocks 1..2048 = weight fp32->bf16 transpose (64x64 tiles).
// Scan runs on one CU concurrently with the BW-bound convert -> hidden.
// ---------------------------------------------------------------------------
struct ScanSmem {
    int   cnts[256][9];
    float wpart[4][8];
    int   totals[8];
    int   sdrop[7168];
    int   dropctr;
};
#define CONV_SMEM (64 * 65 * 4)
#define MID_SMEM ((sizeof(ScanSmem) > CONV_SMEM) ? sizeof(ScanSmem) : CONV_SMEM)

__global__ __launch_bounds__(256) void mid_kernel(
    const int* __restrict__ idx, const float* __restrict__ gate_top,
    const float* __restrict__ gates_psum,
    float* __restrict__ gate_final, int* __restrict__ token_list,
    int* __restrict__ kept, float* __restrict__ out,
    const float* __restrict__ w1, unsigned short* __restrict__ w1t,
    const float* __restrict__ w2, unsigned short* __restrict__ w2t)
{
    __shared__ __align__(16) char smem[MID_SMEM];

    if (blockIdx.x == 0) {
        // ------------------------- scan -------------------------
        ScanSmem& S = *reinterpret_cast<ScanSmem*>(smem);
        const int t = threadIdx.x;
        const int wv = t >> 6, ln = t & 63;
        const int base = t * 32;

        for (int i = t; i < E_NUM * CAP; i += 256) token_list[i] = S_TOK;
        if (t == 0) S.dropctr = 0;

        int c[8];
#pragma unroll
        for (int e = 0; e < 8; ++e) c[e] = 0;
        for (int i = 0; i < 32; ++i) {
            const int ei = idx[base + i];
#pragma unroll
            for (int e = 0; e < 8; ++e) c[e] += (ei == e) ? 1 : 0;
        }
        float g[8];
#pragma unroll
        for (int e = 0; e < 8; ++e) g[e] = 0.f;
        for (int i = 0; i < NGATE_BLK / 256; ++i) {
            const float* gp = gates_psum + (size_t)(t + 256 * i) * 8;
            const float4 a = *(const float4*)gp;
            const float4 b = *(const float4*)(gp + 4);
            g[0] += a.x; g[1] += a.y; g[2] += a.z; g[3] += a.w;
            g[4] += b.x; g[5] += b.y; g[6] += b.z; g[7] += b.w;
        }
#pragma unroll
        for (int e = 0; e < 8; ++e) S.cnts[t][e] = c[e];
#pragma unroll
        for (int e = 0; e < 8; ++e) {
            float v = g[e];
#pragma unroll
            for (int off = 1; off < 64; off <<= 1) v += __shfl_xor(v, off, 64);
            if (ln == 0) S.wpart[wv][e] = v;
        }
        __syncthreads();

#pragma unroll
        for (int ee = 0; ee < 2; ++ee) {
            const int e = wv * 2 + ee;
            int off = 0;
#pragma unroll
            for (int seg = 0; seg < 4; ++seg) {
                const int r = seg * 64 + ln;
                const int v = S.cnts[r][e];
                int incl = v;
#pragma unroll
                for (int d = 1; d < 64; d <<= 1) {
                    const int nn = __shfl_up(incl, d, 64);
                    if (ln >= d) incl += nn;
                }
                S.cnts[r][e] = incl - v + off;
                off += __shfl(incl, 63, 64);
            }
            if (ln == 0) {
                S.totals[e] = off;
                kept[e] = off < CAP ? off : CAP;
            }
        }
        __syncthreads();

        if (t == 0) {
            float l = 0.f;
            for (int e = 0; e < 8; ++e) {
                const float ms = S.wpart[0][e] + S.wpart[1][e] +
                                 S.wpart[2][e] + S.wpart[3][e];
                const int ke = S.totals[e] < CAP ? S.totals[e] : CAP;
                l += (ms / (float)S_TOK) * ((float)ke / (float)S_TOK);
            }
            out[(size_t)S_TOK * M_DIM] = l * (float)E_NUM;
        }

        int rc[8];
#pragma unroll
        for (int e = 0; e < 8; ++e) rc[e] = S.cnts[t][e];

        for (int i = 0; i < 32; ++i) {
            const int s = base + i;
            const int ei = idx[s];
            int loc = 0;
#pragma unroll
            for (int e = 0; e < 8; ++e) {
                if (ei == e) { loc = rc[e]; rc[e] = rc[e] + 1; }
            }
            const bool keepit = loc < CAP;
            gate_final[s] = keepit ? gate_top[s] : 0.f;
            if (keepit) {
                token_list[ei * CAP + loc] = s;
            } else {
                const int d = atomicAdd(&S.dropctr, 1);
                S.sdrop[d] = s;
            }
        }
        __syncthreads();

        const int nd = S.dropctr;
        for (int d = wv; d < nd; d += 4) {
            const int s = S.sdrop[d];
            float4 z = make_float4(0.f, 0.f, 0.f, 0.f);
            *(float4*)(out + (size_t)s * M_DIM + ln * 4) = z;
            *(float4*)(out + (size_t)s * M_DIM + 256 + ln * 4) = z;
        }
    } else {
        // --------------------- weight convert ---------------------
        float (*tile)[65] = reinterpret_cast<float(*)[65]>(smem);
        int b = blockIdx.x - 1;
        const float* src; unsigned short* dst;
        int e, k0, n0, K, N;
        if (b < 1024) {                 // w1: K=512 (8 kt), N=1024 (16 nt)
            e = b >> 7; const int rem = b & 127;
            k0 = (rem >> 4) * 64; n0 = (rem & 15) * 64;
            K = 512; N = 1024; src = w1; dst = w1t;
        } else {                        // w2: K=1024 (16 kt), N=512 (8 nt)
            b -= 1024;
            e = b >> 7; const int rem = b & 127;
            k0 = (rem >> 3) * 64; n0 = (rem & 7) * 64;
            K = 1024; N = 512; src = w2; dst = w2t;
        }
        const int t = threadIdx.x;
        const int r = t >> 4, c4 = (t & 15) * 4;
#pragma unroll
        for (int i = 0; i < 4; ++i) {
            const int row = r + i * 16;
            const float4 v = *(const float4*)(src + ((size_t)e * K + k0 + row) * N + n0 + c4);
            tile[row][c4 + 0] = v.x; tile[row][c4 + 1] = v.y;
            tile[row][c4 + 2] = v.z; tile[row][c4 + 3] = v.w;
        }
        __syncthreads();
#pragma unroll
        for (int i = 0; i < 4; ++i) {
            const int row = r + i * 16;
            ushort4 o;
            o.x = f2bf(tile[c4 + 0][row]); o.y = f2bf(tile[c4 + 1][row]);
            o.z = f2bf(tile[c4 + 2][row]); o.w = f2bf(tile[c4 + 3][row]);
            *(ushort4*)(dst + ((size_t)e * N + n0 + row) * K + k0 + c4) = o;
        }
    }
}

// ---------------------------------------------------------------------------
// K3: MFMA grouped GEMM1 + bias + ReLU -> h (bf16).
// 128x64 tile, BK=64, single-buffer swizzled LDS (24.5 KB, 4 blocks/CU),
// v_mfma_f32_32x32x16_bf16. Wave-tile 64x32.
// ---------------------------------------------------------------------------
__global__ __launch_bounds__(256, 4) void ffn1_mfma(
    const unsigned short* __restrict__ xb, const unsigned short* __restrict__ w1t,
    const float* __restrict__ b1, const int* __restrict__ tok,
    const int* __restrict__ kept, unsigned short* __restrict__ h)
{
    const int b = blockIdx.x;          // 1024 = (8ct*16nt) | 8e
    const int e = b & 7;
    const int r = b >> 3;
    const int ct = r >> 4, nt = r & 15;
    const int c0 = ct * 128, n0 = nt * 64;
    if (c0 >= kept[e]) return;

    __shared__ __align__(16) short Alds[128 * 64];
    __shared__ __align__(16) short Blds[64 * 64];
    __shared__ int srow[128];

    const int t = threadIdx.x;
    const int wave = t >> 6, lane = t & 63;
    const int wm = wave & 1, wn = wave >> 1;
    const int l31 = lane & 31, kh = lane >> 5;

    if (t < 128) srow[t] = tok[e * CAP + c0 + t];
    __syncthreads();

    f32x16 acc[2];
#pragma unroll
    for (int mg = 0; mg < 2; ++mg)
#pragma unroll
        for (int i = 0; i < 16; ++i) acc[mg][i] = 0.f;

    for (int kb = 0; kb < M_DIM; kb += 64) {
        __syncthreads();
#pragma unroll
        for (int i = 0; i < 4; ++i) {
            const int lin = (i * 4 + wave) * 64 + lane;
            const int row = lin >> 3;
            const int ch = (lin & 7) ^ (row & 7);
            async_copy16(xb + (size_t)srow[row] * M_DIM + kb + ch * 8,
                         &Alds[lin * 8]);
        }
#pragma unroll
        for (int i = 0; i < 2; ++i) {
            const int lin = (i * 4 + wave) * 64 + lane;
            const int row = lin >> 3;
            const int ch = (lin & 7) ^ (row & 7);
            async_copy16(w1t + ((size_t)e * H_DIM + n0 + row) * M_DIM + kb + ch * 8,
                         &Blds[lin * 8]);
        }
        __syncthreads();

#pragma unroll
        for (int kk = 0; kk < 64; kk += 16) {
            const int ch = (kk >> 3) + kh;
            bf16x8 af[2], bfv;
#pragma unroll
            for (int mg = 0; mg < 2; ++mg) {
                const int R = wm * 64 + mg * 32 + l31;
                af[mg] = *(const bf16x8*)(&Alds[(R * 8 + (ch ^ (R & 7))) * 8]);
            }
            {
                const int R = wn * 32 + l31;
                bfv = *(const bf16x8*)(&Blds[(R * 8 + (ch ^ (R & 7))) * 8]);
            }
#pragma unroll
            for (int mg = 0; mg < 2; ++mg)
                acc[mg] = __builtin_amdgcn_mfma_f32_32x32x16_bf16(
                    af[mg], bfv, acc[mg], 0, 0, 0);
        }
    }

    const int col = n0 + wn * 32 + l31;
    const float bias = b1[e * H_DIM + col];
#pragma unroll
    for (int mg = 0; mg < 2; ++mg) {
#pragma unroll
        for (int reg = 0; reg < 16; ++reg) {
            const int rowl = wm * 64 + mg * 32 + (reg & 3) + 8 * (reg >> 2) + 4 * kh;
            const float v = fmaxf(acc[mg][reg] + bias, 0.f);
            h[(size_t)(e * CAP + c0 + rowl) * H_DIM + col] = f2bf(v);
        }
    }
}

// ---------------------------------------------------------------------------
// K4: MFMA grouped GEMM2, 64x64 tile, BK=64, single-buffer swizzled LDS,
// 32x32x16 MFMA, gate-scaled scatter. Wave-tile 32x32.
// ---------------------------------------------------------------------------
__global__ __launch_bounds__(256, 4) void ffn2_mfma(
    const unsigned short* __restrict__ h, const unsigned short* __restrict__ w2t,
    const float* __restrict__ b2, const int* __restrict__ tok,
    const int* __restrict__ kept, const float* __restrict__ gate_final,
    float* __restrict__ out)
{
    const int b = blockIdx.x;          // 1024 = (16ct*8nt) | 8e
    const int e = b & 7;
    const int r = b >> 3;
    const int ct = r >> 3, nt = r & 7;
    const int c0 = ct * 64, n0 = nt * 64;
    if (c0 >= kept[e]) return;

    __shared__ __align__(16) short Alds[64 * 64];
    __shared__ __align__(16) short Blds[64 * 64];
    __shared__ int   stok[64];
    __shared__ float sgf[64];

    const int t = threadIdx.x;
    const int wave = t >> 6, lane = t & 63;
    const int wm = wave & 1, wn = wave >> 1;
    const int l31 = lane & 31, kh = lane >> 5;

    if (t < 64) {
        const int tk = tok[e * CAP + c0 + t];
        stok[t] = tk;
        sgf[t] = (tk != S_TOK) ? gate_final[tk] : 0.f;
    }

    f32x16 acc;
#pragma unroll
    for (int i = 0; i < 16; ++i) acc[i] = 0.f;

    for (int kb = 0; kb < H_DIM; kb += 64) {
        __syncthreads();
#pragma unroll
        for (int i = 0; i < 2; ++i) {
            const int lin = (i * 4 + wave) * 64 + lane;
            const int row = lin >> 3;
            const int ch = (lin & 7) ^ (row & 7);
            async_copy16(h + (size_t)(e * CAP + c0 + row) * H_DIM + kb + ch * 8,
                         &Alds[lin * 8]);
        }
#pragma unroll
        for (int i = 0; i < 2; ++i) {
            const int lin = (i * 4 + wave) * 64 + lane;
            const int row = lin >> 3;
            const int ch = (lin & 7) ^ (row & 7);
            async_copy16(w2t + ((size_t)e * M_DIM + n0 + row) * H_DIM + kb + ch * 8,
                         &Blds[lin * 8]);
        }
        __syncthreads();

#pragma unroll
        for (int kk = 0; kk < 64; kk += 16) {
            const int ch = (kk >> 3) + kh;
            bf16x8 af, bfv;
            {
                const int R = wm * 32 + l31;
                af = *(const bf16x8*)(&Alds[(R * 8 + (ch ^ (R & 7))) * 8]);
            }
            {
                const int R = wn * 32 + l31;
                bfv = *(const bf16x8*)(&Blds[(R * 8 + (ch ^ (R & 7))) * 8]);
            }
            acc = __builtin_amdgcn_mfma_f32_32x32x16_bf16(af, bfv, acc, 0, 0, 0);
        }
    }

    const int col = n0 + wn * 32 + l31;
    const float bias = b2[e * M_DIM + col];
#pragma unroll
    for (int reg = 0; reg < 16; ++reg) {
        const int slot = wm * 32 + (reg & 3) + 8 * (reg >> 2) + 4 * kh;
        const int tokid = stok[slot];
        if (tokid != S_TOK) {
            out[(size_t)tokid * M_DIM + col] = sgf[slot] * (acc[reg] + bias);
        }
    }
}

// ---------------------------------------------------------------------------
extern "C" void kernel_launch(void* const* d_in, const int* in_sizes, int n_in,
                              void* d_out, int out_size, void* d_ws, size_t ws_size,
                              hipStream_t stream) {
    const float* feats = (const float*)d_in[0];
    const float* wg    = (const float*)d_in[1];
    const float* w1    = (const float*)d_in[2];
    const float* b1    = (const float*)d_in[3];
    const float* w2    = (const float*)d_in[4];
    const float* b2    = (const float*)d_in[5];
    float* out = (float*)d_out;

    char* ws = (char*)d_ws;
    size_t off = 0;
    unsigned short* h   = (unsigned short*)(ws + off); off += (size_t)E_NUM * CAP * H_DIM * 2;
    unsigned short* xb  = (unsigned short*)(ws + off); off += (size_t)(S_TOK + 1) * M_DIM * 2;
    unsigned short* w1t = (unsigned short*)(ws + off); off += (size_t)E_NUM * H_DIM * M_DIM * 2;
    unsigned short* w2t = (unsigned short*)(ws + off); off += (size_t)E_NUM * M_DIM * H_DIM * 2;
    int*   idx        = (int*)(ws + off);   off += (size_t)S_TOK * 4;
    float* gate_top   = (float*)(ws + off); off += (size_t)S_TOK * 4;
    float* gate_final = (float*)(ws + off); off += (size_t)S_TOK * 4;
    float* gates_psum = (float*)(ws + off); off += (size_t)NGATE_BLK * 8 * 4;
    int*   token_list = (int*)(ws + off);   off += (size_t)S_TOK * 4;
    int*   kept       = (int*)(ws + off);   off += 64;
    (void)ws_size; (void)n_in; (void)in_sizes;

    gate_kernel<<<NGATE_BLK, 256, 0, stream>>>(feats, wg, idx, gate_top,
                                               gates_psum, xb);
    mid_kernel<<<1 + 2048, 256, 0, stream>>>(idx, gate_top, gates_psum,
                                             gate_final, token_list, kept, out,
                                             w1, w1t, w2, w2t);
    ffn1_mfma<<<1024, 256, 0, stream>>>(xb, w1t, b1, token_list, kept, h);
    ffn2_mfma<<<1024, 256, 0, stream>>>(h, w2t, b2, token_list, kept,
                                        gate_final, out);
}

// Round 10
// 167.371 us; speedup vs baseline: 1.0657x; 1.0657x over previous
//
#include <hip/hip_runtime.h>

#define S_TOK 8192
#define M_DIM 512
#define E_NUM 8
#define CAP   1024
#define H_DIM 1024
#define NGATE_BLK (S_TOK / 4)

typedef __attribute__((ext_vector_type(8))) short bf16x8;
typedef __attribute__((ext_vector_type(16))) float f32x16;

__device__ static inline unsigned short f2bf(float f) {
    unsigned int u = __float_as_uint(f);
    unsigned int r = (u + 0x7fffu + ((u >> 16) & 1u)) >> 16;
    return (unsigned short)r;
}

__device__ static inline void async_copy16(const void* g, void* l) {
    __builtin_amdgcn_global_load_lds(
        (const __attribute__((address_space(1))) void*)g,
        (__attribute__((address_space(3))) void*)l, 16, 0, 0);
}

// ---------------------------------------------------------------------------
// K1 "prep": fused gating (+x->bf16) and weight convert/transpose (64x64).
// ---------------------------------------------------------------------------
__global__ __launch_bounds__(256) void prep_kernel(
    const float* __restrict__ feats, const float* __restrict__ wg,
    int* __restrict__ idx, float* __restrict__ gate_top,
    float* __restrict__ gates_psum, unsigned short* __restrict__ xb,
    const float* __restrict__ w1, unsigned short* __restrict__ w1t,
    const float* __restrict__ w2, unsigned short* __restrict__ w2t)
{
    __shared__ float gsh[4][8];
    __shared__ float tile[64][65];

    if (blockIdx.x < NGATE_BLK) {
        const int wave = threadIdx.x >> 6;
        const int lane = threadIdx.x & 63;
        const int s = blockIdx.x * 4 + wave;

        const float* xrow = feats + (size_t)s * M_DIM;
        const int m0 = lane * 8;

        const float4 va = *(const float4*)(xrow + m0);
        const float4 vb = *(const float4*)(xrow + m0 + 4);
        float xv[8] = {va.x, va.y, va.z, va.w, vb.x, vb.y, vb.z, vb.w};

        {
            bf16x8 o;
#pragma unroll
            for (int j = 0; j < 8; ++j) o[j] = (short)f2bf(xv[j]);
            *(bf16x8*)(xb + (size_t)s * M_DIM + m0) = o;
            if (blockIdx.x == 0 && wave == 0) {
                bf16x8 z = (bf16x8){0,0,0,0,0,0,0,0};
                *(bf16x8*)(xb + (size_t)S_TOK * M_DIM + m0) = z;
            }
        }

        float p[8];
#pragma unroll
        for (int e = 0; e < 8; ++e) p[e] = 0.f;
#pragma unroll
        for (int j = 0; j < 8; ++j) {
            const float4 wa = *(const float4*)(wg + (m0 + j) * 8);
            const float4 wb2 = *(const float4*)(wg + (m0 + j) * 8 + 4);
            const float x = xv[j];
            p[0] += x * wa.x;  p[1] += x * wa.y;  p[2] += x * wa.z;  p[3] += x * wa.w;
            p[4] += x * wb2.x; p[5] += x * wb2.y; p[6] += x * wb2.z; p[7] += x * wb2.w;
        }
#pragma unroll
        for (int e = 0; e < 8; ++e) {
            float v = p[e];
#pragma unroll
            for (int off = 1; off < 64; off <<= 1) v += __shfl_xor(v, off, 64);
            p[e] = v;
        }
        if (lane == 0) {
            float mx = p[0];
#pragma unroll
            for (int e = 1; e < 8; ++e) mx = fmaxf(mx, p[e]);
            float ex[8], sum = 0.f;
#pragma unroll
            for (int e = 0; e < 8; ++e) { ex[e] = expf(p[e] - mx); sum += ex[e]; }
            const float inv = 1.0f / sum;
            int best = 0; float bl = p[0];
#pragma unroll
            for (int e = 1; e < 8; ++e) { if (p[e] > bl) { bl = p[e]; best = e; } }
#pragma unroll
            for (int e = 0; e < 8; ++e) gsh[wave][e] = ex[e] * inv;
            idx[s] = best;
            gate_top[s] = ex[best] * inv;
        }
        __syncthreads();
        if (threadIdx.x < 8) {
            const int e = threadIdx.x;
            gates_psum[blockIdx.x * 8 + e] =
                gsh[0][e] + gsh[1][e] + gsh[2][e] + gsh[3][e];
        }
    } else {
        int b = blockIdx.x - NGATE_BLK;
        const float* src; unsigned short* dst;
        int e, k0, n0, K, N;
        if (b < 1024) {
            e = b >> 7; const int rem = b & 127;
            k0 = (rem >> 4) * 64; n0 = (rem & 15) * 64;
            K = 512; N = 1024; src = w1; dst = w1t;
        } else {
            b -= 1024;
            e = b >> 7; const int rem = b & 127;
            k0 = (rem >> 3) * 64; n0 = (rem & 7) * 64;
            K = 1024; N = 512; src = w2; dst = w2t;
        }
        const int t = threadIdx.x;
        const int r = t >> 4, c4 = (t & 15) * 4;
#pragma unroll
        for (int i = 0; i < 4; ++i) {
            const int row = r + i * 16;
            const float4 v = *(const float4*)(src + ((size_t)e * K + k0 + row) * N + n0 + c4);
            tile[row][c4 + 0] = v.x; tile[row][c4 + 1] = v.y;
            tile[row][c4 + 2] = v.z; tile[row][c4 + 3] = v.w;
        }
        __syncthreads();
#pragma unroll
        for (int i = 0; i < 4; ++i) {
            const int row = r + i * 16;
            ushort4 o;
            o.x = f2bf(tile[c4 + 0][row]); o.y = f2bf(tile[c4 + 1][row]);
            o.z = f2bf(tile[c4 + 2][row]); o.w = f2bf(tile[c4 + 3][row]);
            *(ushort4*)(dst + ((size_t)e * N + n0 + row) * K + k0 + c4) = o;
        }
    }
}

// ---------------------------------------------------------------------------
// K2: FAST single-workgroup scan. Register-prefetched vectorized loads
// (8x int4 + 8x float4 per thread -> 16 outstanding loads, one latency
// round instead of 64 serial), phase C from registers, gate_final staged
// in LDS then written coalesced. Dropped list in global ws.
// ---------------------------------------------------------------------------
__global__ __launch_bounds__(256) void scan_kernel(
    const int* __restrict__ idx, const float* __restrict__ gate_top,
    const float* __restrict__ gates_psum,
    float* __restrict__ gate_final, int* __restrict__ token_list,
    int* __restrict__ kept, float* __restrict__ out,
    int* __restrict__ dropped)
{
    __shared__ int   cnts[256][9];
    __shared__ float wpart[4][8];
    __shared__ int   totals[8];
    __shared__ float gfbuf[8192];
    __shared__ int   dropctr;

    const int t = threadIdx.x;
    const int wv = t >> 6, ln = t & 63;
    const int base = t * 32;

    if (t == 0) dropctr = 0;

    // register prefetch: this thread's 32 tokens (idx + gate)
    int4   vi[8];
    float4 vg[8];
#pragma unroll
    for (int i = 0; i < 8; ++i) vi[i] = ((const int4*)(idx + base))[i];
#pragma unroll
    for (int i = 0; i < 8; ++i) vg[i] = ((const float4*)(gate_top + base))[i];

    // token_list prefill (coalesced int4)
    {
        const int4 s4 = make_int4(S_TOK, S_TOK, S_TOK, S_TOK);
#pragma unroll
        for (int i = 0; i < 8; ++i) ((int4*)token_list)[t + 256 * i] = s4;
    }

    // phase A: per-chunk counts from registers
    int c[8];
#pragma unroll
    for (int e = 0; e < 8; ++e) c[e] = 0;
#pragma unroll
    for (int i = 0; i < 8; ++i) {
#pragma unroll
        for (int e = 0; e < 8; ++e)
            c[e] += (vi[i].x == e) + (vi[i].y == e) + (vi[i].z == e) + (vi[i].w == e);
    }

    // gates partial sums (coalesced)
    float g[8];
#pragma unroll
    for (int e = 0; e < 8; ++e) g[e] = 0.f;
#pragma unroll
    for (int i = 0; i < NGATE_BLK / 256; ++i) {
        const float* gp = gates_psum + (size_t)(t + 256 * i) * 8;
        const float4 a = *(const float4*)gp;
        const float4 b = *(const float4*)(gp + 4);
        g[0] += a.x; g[1] += a.y; g[2] += a.z; g[3] += a.w;
        g[4] += b.x; g[5] += b.y; g[6] += b.z; g[7] += b.w;
    }
#pragma unroll
    for (int e = 0; e < 8; ++e) cnts[t][e] = c[e];
#pragma unroll
    for (int e = 0; e < 8; ++e) {
        float v = g[e];
#pragma unroll
        for (int off = 1; off < 64; off <<= 1) v += __shfl_xor(v, off, 64);
        if (ln == 0) wpart[wv][e] = v;
    }
    __syncthreads();

    // phase B: parallel exclusive scan over 256 chunks; wave wv owns 2 experts
#pragma unroll
    for (int ee = 0; ee < 2; ++ee) {
        const int e = wv * 2 + ee;
        int off = 0;
#pragma unroll
        for (int seg = 0; seg < 4; ++seg) {
            const int r = seg * 64 + ln;
            const int v = cnts[r][e];
            int incl = v;
#pragma unroll
            for (int d = 1; d < 64; d <<= 1) {
                const int nn = __shfl_up(incl, d, 64);
                if (ln >= d) incl += nn;
            }
            cnts[r][e] = incl - v + off;
            off += __shfl(incl, 63, 64);
        }
        if (ln == 0) {
            totals[e] = off;
            kept[e] = off < CAP ? off : CAP;
        }
    }
    __syncthreads();

    if (t == 0) {
        float l = 0.f;
        for (int e = 0; e < 8; ++e) {
            const float ms = wpart[0][e] + wpart[1][e] + wpart[2][e] + wpart[3][e];
            const int ke = totals[e] < CAP ? totals[e] : CAP;
            l += (ms / (float)S_TOK) * ((float)ke / (float)S_TOK);
        }
        out[(size_t)S_TOK * M_DIM] = l * (float)E_NUM;   // l_aux
    }

    // phase C: arrival-order slot assignment from registers
    int rc[8];
#pragma unroll
    for (int e = 0; e < 8; ++e) rc[e] = cnts[t][e];

#pragma unroll
    for (int i = 0; i < 8; ++i) {
        const int   ev[4] = {vi[i].x, vi[i].y, vi[i].z, vi[i].w};
        const float gv[4] = {vg[i].x, vg[i].y, vg[i].z, vg[i].w};
#pragma unroll
        for (int j = 0; j < 4; ++j) {
            const int s = base + i * 4 + j;
            const int ei = ev[j];
            int loc = 0;
#pragma unroll
            for (int e = 0; e < 8; ++e) {
                if (ei == e) { loc = rc[e]; rc[e] = rc[e] + 1; }
            }
            const bool keepit = loc < CAP;
            gfbuf[s] = keepit ? gv[j] : 0.f;
            if (keepit) {
                token_list[ei * CAP + loc] = s;
            } else {
                const int d = atomicAdd(&dropctr, 1);
                dropped[d] = s;
            }
        }
    }
    __syncthreads();

    // coalesced gate_final writeback from LDS
#pragma unroll
    for (int i = 0; i < 8; ++i) {
        const int o = (t + 256 * i) * 4;
        *(float4*)(gate_final + o) = *(const float4*)(gfbuf + o);
    }

    // zero dropped rows: one wave per row
    const int nd = dropctr;
    for (int d = wv; d < nd; d += 4) {
        const int s = dropped[d];
        float4 z = make_float4(0.f, 0.f, 0.f, 0.f);
        *(float4*)(out + (size_t)s * M_DIM + ln * 4) = z;
        *(float4*)(out + (size_t)s * M_DIM + 256 + ln * 4) = z;
    }
}

// ---------------------------------------------------------------------------
// K3: MFMA grouped GEMM1 + bias + ReLU -> h (bf16).
// 128x64 tile, BK=64, single-buffer swizzled LDS (24.5 KB, 4 blocks/CU),
// v_mfma_f32_32x32x16_bf16. Wave-tile 64x32.
// ---------------------------------------------------------------------------
__global__ __launch_bounds__(256, 4) void ffn1_mfma(
    const unsigned short* __restrict__ xb, const unsigned short* __restrict__ w1t,
    const float* __restrict__ b1, const int* __restrict__ tok,
    const int* __restrict__ kept, unsigned short* __restrict__ h)
{
    const int b = blockIdx.x;          // 1024 = (8ct*16nt) | 8e
    const int e = b & 7;
    const int r = b >> 3;
    const int ct = r >> 4, nt = r & 15;
    const int c0 = ct * 128, n0 = nt * 64;
    if (c0 >= kept[e]) return;

    __shared__ __align__(16) short Alds[128 * 64];
    __shared__ __align__(16) short Blds[64 * 64];
    __shared__ int srow[128];

    const int t = threadIdx.x;
    const int wave = t >> 6, lane = t & 63;
    const int wm = wave & 1, wn = wave >> 1;
    const int l31 = lane & 31, kh = lane >> 5;

    if (t < 128) srow[t] = tok[e * CAP + c0 + t];
    __syncthreads();

    f32x16 acc[2];
#pragma unroll
    for (int mg = 0; mg < 2; ++mg)
#pragma unroll
        for (int i = 0; i < 16; ++i) acc[mg][i] = 0.f;

    for (int kb = 0; kb < M_DIM; kb += 64) {
        __syncthreads();
#pragma unroll
        for (int i = 0; i < 4; ++i) {
            const int lin = (i * 4 + wave) * 64 + lane;
            const int row = lin >> 3;
            const int ch = (lin & 7) ^ (row & 7);
            async_copy16(xb + (size_t)srow[row] * M_DIM + kb + ch * 8,
                         &Alds[lin * 8]);
        }
#pragma unroll
        for (int i = 0; i < 2; ++i) {
            const int lin = (i * 4 + wave) * 64 + lane;
            const int row = lin >> 3;
            const int ch = (lin & 7) ^ (row & 7);
            async_copy16(w1t + ((size_t)e * H_DIM + n0 + row) * M_DIM + kb + ch * 8,
                         &Blds[lin * 8]);
        }
        __syncthreads();

#pragma unroll
        for (int kk = 0; kk < 64; kk += 16) {
            const int ch = (kk >> 3) + kh;
            bf16x8 af[2], bfv;
#pragma unroll
            for (int mg = 0; mg < 2; ++mg) {
                const int R = wm * 64 + mg * 32 + l31;
                af[mg] = *(const bf16x8*)(&Alds[(R * 8 + (ch ^ (R & 7))) * 8]);
            }
            {
                const int R = wn * 32 + l31;
                bfv = *(const bf16x8*)(&Blds[(R * 8 + (ch ^ (R & 7))) * 8]);
            }
#pragma unroll
            for (int mg = 0; mg < 2; ++mg)
                acc[mg] = __builtin_amdgcn_mfma_f32_32x32x16_bf16(
                    af[mg], bfv, acc[mg], 0, 0, 0);
        }
    }

    const int col = n0 + wn * 32 + l31;
    const float bias = b1[e * H_DIM + col];
#pragma unroll
    for (int mg = 0; mg < 2; ++mg) {
#pragma unroll
        for (int reg = 0; reg < 16; ++reg) {
            const int rowl = wm * 64 + mg * 32 + (reg & 3) + 8 * (reg >> 2) + 4 * kh;
            const float v = fmaxf(acc[mg][reg] + bias, 0.f);
            h[(size_t)(e * CAP + c0 + rowl) * H_DIM + col] = f2bf(v);
        }
    }
}

// ---------------------------------------------------------------------------
// K4: MFMA grouped GEMM2, 64x64 tile, BK=64, single-buffer swizzled LDS,
// 32x32x16 MFMA, gate-scaled scatter. Wave-tile 32x32.
// ---------------------------------------------------------------------------
__global__ __launch_bounds__(256, 4) void ffn2_mfma(
    const unsigned short* __restrict__ h, const unsigned short* __restrict__ w2t,
    const float* __restrict__ b2, const int* __restrict__ tok,
    const int* __restrict__ kept, const float* __restrict__ gate_final,
    float* __restrict__ out)
{
    const int b = blockIdx.x;          // 1024 = (16ct*8nt) | 8e
    const int e = b & 7;
    const int r = b >> 3;
    const int ct = r >> 3, nt = r & 7;
    const int c0 = ct * 64, n0 = nt * 64;
    if (c0 >= kept[e]) return;

    __shared__ __align__(16) short Alds[64 * 64];
    __shared__ __align__(16) short Blds[64 * 64];
    __shared__ int   stok[64];
    __shared__ float sgf[64];

    const int t = threadIdx.x;
    const int wave = t >> 6, lane = t & 63;
    const int wm = wave & 1, wn = wave >> 1;
    const int l31 = lane & 31, kh = lane >> 5;

    if (t < 64) {
        const int tk = tok[e * CAP + c0 + t];
        stok[t] = tk;
        sgf[t] = (tk != S_TOK) ? gate_final[tk] : 0.f;
    }

    f32x16 acc;
#pragma unroll
    for (int i = 0; i < 16; ++i) acc[i] = 0.f;

    for (int kb = 0; kb < H_DIM; kb += 64) {
        __syncthreads();
#pragma unroll
        for (int i = 0; i < 2; ++i) {
            const int lin = (i * 4 + wave) * 64 + lane;
            const int row = lin >> 3;
            const int ch = (lin & 7) ^ (row & 7);
            async_copy16(h + (size_t)(e * CAP + c0 + row) * H_DIM + kb + ch * 8,
                         &Alds[lin * 8]);
        }
#pragma unroll
        for (int i = 0; i < 2; ++i) {
            const int lin = (i * 4 + wave) * 64 + lane;
            const int row = lin >> 3;
            const int ch = (lin & 7) ^ (row & 7);
            async_copy16(w2t + ((size_t)e * M_DIM + n0 + row) * H_DIM + kb + ch * 8,
                         &Blds[lin * 8]);
        }
        __syncthreads();

#pragma unroll
        for (int kk = 0; kk < 64; kk += 16) {
            const int ch = (kk >> 3) + kh;
            bf16x8 af, bfv;
            {
                const int R = wm * 32 + l31;
                af = *(const bf16x8*)(&Alds[(R * 8 + (ch ^ (R & 7))) * 8]);
            }
            {
                const int R = wn * 32 + l31;
                bfv = *(const bf16x8*)(&Blds[(R * 8 + (ch ^ (R & 7))) * 8]);
            }
            acc = __builtin_amdgcn_mfma_f32_32x32x16_bf16(af, bfv, acc, 0, 0, 0);
        }
    }

    const int col = n0 + wn * 32 + l31;
    const float bias = b2[e * M_DIM + col];
#pragma unroll
    for (int reg = 0; reg < 16; ++reg) {
        const int slot = wm * 32 + (reg & 3) + 8 * (reg >> 2) + 4 * kh;
        const int tokid = stok[slot];
        if (tokid != S_TOK) {
            out[(size_t)tokid * M_DIM + col] = sgf[slot] * (acc[reg] + bias);
        }
    }
}

// ---------------------------------------------------------------------------
extern "C" void kernel_launch(void* const* d_in, const int* in_sizes, int n_in,
                              void* d_out, int out_size, void* d_ws, size_t ws_size,
                              hipStream_t stream) {
    const float* feats = (const float*)d_in[0];
    const float* wg    = (const float*)d_in[1];
    const float* w1    = (const float*)d_in[2];
    const float* b1    = (const float*)d_in[3];
    const float* w2    = (const float*)d_in[4];
    const float* b2    = (const float*)d_in[5];
    float* out = (float*)d_out;

    char* ws = (char*)d_ws;
    size_t off = 0;
    unsigned short* h   = (unsigned short*)(ws + off); off += (size_t)E_NUM * CAP * H_DIM * 2;
    unsigned short* xb  = (unsigned short*)(ws + off); off += (size_t)(S_TOK + 1) * M_DIM * 2;
    unsigned short* w1t = (unsigned short*)(ws + off); off += (size_t)E_NUM * H_DIM * M_DIM * 2;
    unsigned short* w2t = (unsigned short*)(ws + off); off += (size_t)E_NUM * M_DIM * H_DIM * 2;
    int*   idx        = (int*)(ws + off);   off += (size_t)S_TOK * 4;
    float* gate_top   = (float*)(ws + off); off += (size_t)S_TOK * 4;
    float* gate_final = (float*)(ws + off); off += (size_t)S_TOK * 4;
    float* gates_psum = (float*)(ws + off); off += (size_t)NGATE_BLK * 8 * 4;
    int*   token_list = (int*)(ws + off);   off += (size_t)S_TOK * 4;
    int*   dropped    = (int*)(ws + off);   off += (size_t)S_TOK * 4;
    int*   kept       = (int*)(ws + off);   off += 64;
    (void)ws_size; (void)n_in; (void)in_sizes;

    prep_kernel<<<NGATE_BLK + 2048, 256, 0, stream>>>(
        feats, wg, idx, gate_top, gates_psum, xb, w1, w1t, w2, w2t);
    scan_kernel<<<1, 256, 0, stream>>>(idx, gate_top, gates_psum, gate_final,
                                       token_list, kept, out, dropped);
    ffn1_mfma<<<1024, 256, 0, stream>>>(xb, w1t, b1, token_list, kept, h);
    ffn2_mfma<<<1024, 256, 0, stream>>>(h, w2t, b2, token_list, kept,
                                        gate_final, out);
}